// Round 7
// baseline (103.377 us; speedup 1.0000x reference)
//
#include <hip/hip_runtime.h>

// Problem constants (B=2, H=8, L=1024, D=64)
#define N_HEADS 16          // B*H
#define L_SEQ   1024
#define D_HEAD  64
#define D2      128         // 2*D (sin/cos concat)
#define T_CHUNK 32
#define N_CHUNK (L_SEQ / T_CHUNK)   // 32
#define KV_ELEMS (D2 * D_HEAD)      // 8192

// Padded LDS row: +4 floats every 32 cols; g-group b128 reads land 2-way max.
#define ROWP 140
#define PARTP 132

__device__ __forceinline__ int pad_col(int d2) { return d2 + 4 * (d2 >> 5); }

#define SINCOS_SCALE 1.53398078788564122971e-3f   // (pi/2)/1024

// All-VALU (DPP) reduction over the 8 lanes differing in bits 0..2.
__device__ __forceinline__ float red8_dpp(float x) {
    x += __int_as_float(__builtin_amdgcn_mov_dpp(__float_as_int(x), 0xB1, 0xF, 0xF, true));
    x += __int_as_float(__builtin_amdgcn_mov_dpp(__float_as_int(x), 0x4E, 0xF, 0xF, true));
    x += __int_as_float(__builtin_amdgcn_mov_dpp(__float_as_int(x), 0x141, 0xF, 0xF, true));
    return x;
}

// XCD-affinity decode: 512 blocks, round-robin dispatch puts bid%8 on XCD bid%8.
// Head n lands entirely on XCD n&7 (2 heads/XCD -> 2 MB chunk-sum working set
// per XCD L2; K1 writes and K3 scan-reads stay local).
__device__ __forceinline__ void decode_cn(int bid, int& c, int& n) {
    int xcd = bid & 7, slot = bid >> 3;      // slot 0..63
    n = xcd + ((slot & 1) << 3);             // heads {xcd, xcd+8}
    c = slot >> 1;                           // 0..31
}

// ---------------------------------------------------------------------------
// K1: per-(chunk, head) local sums (RAW, not scanned). 256 threads;
// thread owns 16 d2-cols (g = tid&7) x 2 m-cols.
// ---------------------------------------------------------------------------
__global__ __launch_bounds__(256, 2) void k1_chunk_sums(
    const float* __restrict__ k, const float* __restrict__ v,
    float* __restrict__ sumkv, float* __restrict__ sumk)
{
    __shared__ __attribute__((aligned(16))) float k_s[T_CHUNK][ROWP];
    __shared__ __attribute__((aligned(16))) float v_s[T_CHUNK][D_HEAD];
    __shared__ float s_tab[T_CHUNK], c_tab[T_CHUNK];

    int c, n; decode_cn(blockIdx.x, c, n);
    const int tid = threadIdx.x;
    const int base = (n * L_SEQ + c * T_CHUNK) * D_HEAD;

    // Issue raw global loads first (no dependency on s_tab).
    const float4* k4g = (const float4*)(k + base);
    const float4* v4g = (const float4*)(v + base);
    float4 kr0 = k4g[tid], kr1 = k4g[256 + tid];
    float4 vr0 = v4g[tid], vr1 = v4g[256 + tid];

    if (tid < T_CHUNK) {
        float th = SINCOS_SCALE * (float)(c * T_CHUNK + tid + 1);
        s_tab[tid] = __sinf(th);
        c_tab[tid] = __cosf(th);
    }
    __syncthreads();

#pragma unroll
    for (int j = 0; j < 2; ++j) {
        int i4 = j * 256 + tid;            // 0..511
        int l = i4 >> 4, d = (i4 & 15) << 2;
        float4 kk = j ? kr1 : kr0;
        float4 vv = j ? vr1 : vr0;
        kk.x = fmaxf(kk.x, 0.f); kk.y = fmaxf(kk.y, 0.f);
        kk.z = fmaxf(kk.z, 0.f); kk.w = fmaxf(kk.w, 0.f);
        vv.x = fmaxf(vv.x, 0.f); vv.y = fmaxf(vv.y, 0.f);
        vv.z = fmaxf(vv.z, 0.f); vv.w = fmaxf(vv.w, 0.f);
        float s = s_tab[l], cs = c_tab[l];
        *(float4*)&k_s[l][pad_col(d)]      = make_float4(kk.x*s,  kk.y*s,  kk.z*s,  kk.w*s);
        *(float4*)&k_s[l][pad_col(d + 64)] = make_float4(kk.x*cs, kk.y*cs, kk.z*cs, kk.w*cs);
        *(float4*)&v_s[l][d] = vv;
    }
    __syncthreads();

    // Column sums of k_ -> sumk (raw per-chunk), computed once.
    if (tid < D2) {
        int pc = pad_col(tid);
        float ks = 0.f;
#pragma unroll
        for (int l = 0; l < T_CHUNK; ++l) ks += k_s[l][pc];
        sumk[(n * N_CHUNK + c) * D2 + tid] = ks;
    }

    const int g = tid & 7, mh = (tid >> 3) << 1;
    const int gbase = pad_col(16 * g);

    float st0[16], st1[16];
#pragma unroll
    for (int j = 0; j < 16; ++j) { st0[j] = 0.f; st1[j] = 0.f; }

    for (int l = 0; l < T_CHUNK; ++l) {
        float2 vm = *(const float2*)&v_s[l][mh];
        const float4* kv4 = (const float4*)&k_s[l][gbase];
#pragma unroll
        for (int jj = 0; jj < 4; ++jj) {
            float4 kk = kv4[jj];
            st0[4*jj+0] = fmaf(kk.x, vm.x, st0[4*jj+0]);
            st1[4*jj+0] = fmaf(kk.x, vm.y, st1[4*jj+0]);
            st0[4*jj+1] = fmaf(kk.y, vm.x, st0[4*jj+1]);
            st1[4*jj+1] = fmaf(kk.y, vm.y, st1[4*jj+1]);
            st0[4*jj+2] = fmaf(kk.z, vm.x, st0[4*jj+2]);
            st1[4*jj+2] = fmaf(kk.z, vm.y, st1[4*jj+2]);
            st0[4*jj+3] = fmaf(kk.w, vm.x, st0[4*jj+3]);
            st1[4*jj+3] = fmaf(kk.w, vm.y, st1[4*jj+3]);
        }
    }

    // Coalesced float4 stores, thread-interleaved flat layout (K3 mirrors it).
    float4* dst = (float4*)(sumkv + (size_t)(n * N_CHUNK + c) * KV_ELEMS);
#pragma unroll
    for (int j4 = 0; j4 < 4; ++j4) {
        dst[(2*j4+0)*256 + tid] = make_float4(st0[4*j4], st0[4*j4+1], st0[4*j4+2], st0[4*j4+3]);
        dst[(2*j4+1)*256 + tid] = make_float4(st1[4*j4], st1[4*j4+1], st1[4*j4+2], st1[4*j4+3]);
    }
}

// ---------------------------------------------------------------------------
// K3: outputs. Each block computes its own exclusive prefix by summing the
// preceding chunk-sum blocks straight from (XCD-local) L2 -- K2 is gone.
// ---------------------------------------------------------------------------
__global__ __launch_bounds__(256, 2) void k3_output(
    const float* __restrict__ q, const float* __restrict__ k,
    const float* __restrict__ v, const float* __restrict__ sumkv,
    const float* __restrict__ sumk, float* __restrict__ out)
{
    __shared__ __attribute__((aligned(16))) float k_s[T_CHUNK][ROWP];
    __shared__ __attribute__((aligned(16))) float q_s[T_CHUNK][ROWP];
    __shared__ __attribute__((aligned(16))) float v_s[T_CHUNK][D_HEAD];
    __shared__ __attribute__((aligned(16))) float pool[T_CHUNK * PARTP]; // part_s / out_s
    __shared__ float rden_s[T_CHUNK];
    __shared__ float s_tab[T_CHUNK], c_tab[T_CHUNK];

    float (*part_s)[PARTP] = (float(*)[PARTP])pool;
    float (*out_s)[D_HEAD] = (float(*)[D_HEAD])pool;

    int c, n; decode_cn(blockIdx.x, c, n);
    const int tid = threadIdx.x;
    const int base = (n * L_SEQ + c * T_CHUNK) * D_HEAD;

    // Issue raw q/k/v loads first (longest-latency, no deps).
    const float4* q4g = (const float4*)(q + base);
    const float4* k4g = (const float4*)(k + base);
    const float4* v4g = (const float4*)(v + base);
    float4 kr0 = k4g[tid], kr1 = k4g[256 + tid];
    float4 qr0 = q4g[tid], qr1 = q4g[256 + tid];
    float4 vr0 = v4g[tid], vr1 = v4g[256 + tid];

    if (tid < T_CHUNK) {
        float th = SINCOS_SCALE * (float)(c * T_CHUNK + tid + 1);
        s_tab[tid] = __sinf(th);
        c_tab[tid] = __cosf(th);
    }

    // ---- Fused exclusive scan: sum preceding chunk-sum blocks (L2-local).
    float st0[16], st1[16];
#pragma unroll
    for (int j = 0; j < 16; ++j) { st0[j] = 0.f; st1[j] = 0.f; }

    const float4* csb = (const float4*)(sumkv + (size_t)n * N_CHUNK * KV_ELEMS);
    if (c > 0) {
        // 2-stage pipeline: 8 float4 in flight while previous 8 accumulate.
        float4 b0,b1,b2,b3,b4,b5,b6,b7;
        {
            const float4* p = csb;
            b0=p[0*256+tid]; b1=p[1*256+tid]; b2=p[2*256+tid]; b3=p[3*256+tid];
            b4=p[4*256+tid]; b5=p[5*256+tid]; b6=p[6*256+tid]; b7=p[7*256+tid];
        }
        for (int cc = 0; cc < c; ++cc) {
            float4 c0=b0,c1=b1,c2=b2,c3=b3,c4=b4,c5=b5,c6=b6,c7=b7;
            if (cc + 1 < c) {
                const float4* p = csb + (size_t)(cc + 1) * (KV_ELEMS / 4);
                b0=p[0*256+tid]; b1=p[1*256+tid]; b2=p[2*256+tid]; b3=p[3*256+tid];
                b4=p[4*256+tid]; b5=p[5*256+tid]; b6=p[6*256+tid]; b7=p[7*256+tid];
            }
            st0[0]+=c0.x;  st0[1]+=c0.y;  st0[2]+=c0.z;  st0[3]+=c0.w;
            st1[0]+=c1.x;  st1[1]+=c1.y;  st1[2]+=c1.z;  st1[3]+=c1.w;
            st0[4]+=c2.x;  st0[5]+=c2.y;  st0[6]+=c2.z;  st0[7]+=c2.w;
            st1[4]+=c3.x;  st1[5]+=c3.y;  st1[6]+=c3.z;  st1[7]+=c3.w;
            st0[8]+=c4.x;  st0[9]+=c4.y;  st0[10]+=c4.z; st0[11]+=c4.w;
            st1[8]+=c5.x;  st1[9]+=c5.y;  st1[10]+=c5.z; st1[11]+=c5.w;
            st0[12]+=c6.x; st0[13]+=c6.y; st0[14]+=c6.z; st0[15]+=c6.w;
            st1[12]+=c7.x; st1[13]+=c7.y; st1[14]+=c7.z; st1[15]+=c7.w;
        }
    }

    // sumk exclusive prefix for this chunk (tid<128), 4-way unrolled.
    float kc = 0.f;
    if (tid < D2) {
        const float* bk = sumk + (size_t)n * N_CHUNK * D2 + tid;
        float k0 = 0.f, k1 = 0.f, k2 = 0.f, k3 = 0.f;
        int cc = 0;
        for (; cc + 4 <= c; cc += 4) {
            k0 += bk[(cc+0) * D2]; k1 += bk[(cc+1) * D2];
            k2 += bk[(cc+2) * D2]; k3 += bk[(cc+3) * D2];
        }
        for (; cc < c; ++cc) k0 += bk[cc * D2];
        kc = (k0 + k1) + (k2 + k3);
    }

    __syncthreads();   // s_tab ready

    // Stage q/k/v (reweighted) into LDS.
#pragma unroll
    for (int j = 0; j < 2; ++j) {
        int i4 = j * 256 + tid;
        int l = i4 >> 4, d = (i4 & 15) << 2;
        float4 kk = j ? kr1 : kr0;
        float4 qq = j ? qr1 : qr0;
        float4 vv = j ? vr1 : vr0;
        kk.x = fmaxf(kk.x, 0.f); kk.y = fmaxf(kk.y, 0.f);
        kk.z = fmaxf(kk.z, 0.f); kk.w = fmaxf(kk.w, 0.f);
        qq.x = fmaxf(qq.x, 0.f); qq.y = fmaxf(qq.y, 0.f);
        qq.z = fmaxf(qq.z, 0.f); qq.w = fmaxf(qq.w, 0.f);
        vv.x = fmaxf(vv.x, 0.f); vv.y = fmaxf(vv.y, 0.f);
        vv.z = fmaxf(vv.z, 0.f); vv.w = fmaxf(vv.w, 0.f);
        float s = s_tab[l], cs = c_tab[l];
        *(float4*)&k_s[l][pad_col(d)]      = make_float4(kk.x*s,  kk.y*s,  kk.z*s,  kk.w*s);
        *(float4*)&k_s[l][pad_col(d + 64)] = make_float4(kk.x*cs, kk.y*cs, kk.z*cs, kk.w*cs);
        *(float4*)&q_s[l][pad_col(d)]      = make_float4(qq.x*s,  qq.y*s,  qq.z*s,  qq.w*s);
        *(float4*)&q_s[l][pad_col(d + 64)] = make_float4(qq.x*cs, qq.y*cs, qq.z*cs, qq.w*cs);
        *(float4*)&v_s[l][d] = vv;
    }
    __syncthreads();

    // Denominator: per-column running k-cumsum * q, once per block.
    if (tid < D2) {
        int pc = pad_col(tid);
#pragma unroll
        for (int l = 0; l < T_CHUNK; ++l) {
            kc += k_s[l][pc];
            part_s[l][tid] = q_s[l][pc] * kc;
        }
    }
    __syncthreads();

    {
        int l = tid >> 3, j = tid & 7;
        const float4* p4 = (const float4*)&part_s[l][j * 16];
        float4 aa = p4[0], bb = p4[1], cc4 = p4[2], dd = p4[3];
        float sum = ((aa.x + aa.y) + (aa.z + aa.w)) + ((bb.x + bb.y) + (bb.z + bb.w))
                  + ((cc4.x + cc4.y) + (cc4.z + cc4.w)) + ((dd.x + dd.y) + (dd.z + dd.w));
        sum = red8_dpp(sum);
        if (j == 0) rden_s[l] = 1.f / fmaxf(sum, 1e-6f);
    }
    __syncthreads();   // part_s dead; pool becomes out_s

    const int g = tid & 7, mh = (tid >> 3) << 1;
    const int gbase = pad_col(16 * g);

    for (int l = 0; l < T_CHUNK; ++l) {
        float2 vm = *(const float2*)&v_s[l][mh];
        const float4* kv4 = (const float4*)&k_s[l][gbase];
        const float4* qv4 = (const float4*)&q_s[l][gbase];
        float a0 = 0.f, a1 = 0.f;
#pragma unroll
        for (int jj = 0; jj < 4; ++jj) {
            float4 kk = kv4[jj];
            float4 qq = qv4[jj];
            st0[4*jj+0] = fmaf(kk.x, vm.x, st0[4*jj+0]); a0 = fmaf(qq.x, st0[4*jj+0], a0);
            st1[4*jj+0] = fmaf(kk.x, vm.y, st1[4*jj+0]); a1 = fmaf(qq.x, st1[4*jj+0], a1);
            st0[4*jj+1] = fmaf(kk.y, vm.x, st0[4*jj+1]); a0 = fmaf(qq.y, st0[4*jj+1], a0);
            st1[4*jj+1] = fmaf(kk.y, vm.y, st1[4*jj+1]); a1 = fmaf(qq.y, st1[4*jj+1], a1);
            st0[4*jj+2] = fmaf(kk.z, vm.x, st0[4*jj+2]); a0 = fmaf(qq.z, st0[4*jj+2], a0);
            st1[4*jj+2] = fmaf(kk.z, vm.y, st1[4*jj+2]); a1 = fmaf(qq.z, st1[4*jj+2], a1);
            st0[4*jj+3] = fmaf(kk.w, vm.x, st0[4*jj+3]); a0 = fmaf(qq.w, st0[4*jj+3], a0);
            st1[4*jj+3] = fmaf(kk.w, vm.y, st1[4*jj+3]); a1 = fmaf(qq.w, st1[4*jj+3], a1);
        }
        a0 = red8_dpp(a0);
        a1 = red8_dpp(a1);
        if (g == 0) {
            float r = rden_s[l];
            *(float2*)&out_s[l][mh] = make_float2(a0 * r, a1 * r);
        }
    }
    __syncthreads();

    // Coalesced output store.
    {
        float4* o4 = (float4*)(out + base);
        const float4* s4o = (const float4*)&out_s[0][0];
        o4[tid] = s4o[tid];
        o4[256 + tid] = s4o[256 + tid];
    }
}

// ---------------------------------------------------------------------------
extern "C" void kernel_launch(void* const* d_in, const int* in_sizes, int n_in,
                              void* d_out, int out_size, void* d_ws, size_t ws_size,
                              hipStream_t stream) {
    (void)in_sizes; (void)n_in; (void)out_size; (void)ws_size;
    const float* q = (const float*)d_in[0];
    const float* k = (const float*)d_in[1];
    const float* v = (const float*)d_in[2];
    float* out = (float*)d_out;

    float* sumkv = (float*)d_ws;                                   // [N][C][8192] flat
    float* sumk  = sumkv + (size_t)N_HEADS * N_CHUNK * KV_ELEMS;   // [N][C][128]

    k1_chunk_sums<<<dim3(N_CHUNK * N_HEADS), 256, 0, stream>>>(k, v, sumkv, sumk);
    k3_output<<<dim3(N_CHUNK * N_HEADS), 256, 0, stream>>>(q, k, v, sumkv, sumk, out);
}

// Round 8
// 96.760 us; speedup vs baseline: 1.0684x; 1.0684x over previous
//
#include <hip/hip_runtime.h>

// Problem constants (B=2, H=8, L=1024, D=64)
#define N_HEADS 16          // B*H
#define L_SEQ   1024
#define D_HEAD  64
#define D2      128         // 2*D (sin/cos concat)
#define T_CHUNK 32
#define N_CHUNK (L_SEQ / T_CHUNK)   // 32
#define KV_ELEMS (D2 * D_HEAD)      // 8192

// Padded LDS row: +4 floats every 32 cols; g-group b128 reads land 2-way max.
#define ROWP 140
#define PARTP 132

__device__ __forceinline__ int pad_col(int d2) { return d2 + 4 * (d2 >> 5); }

#define SINCOS_SCALE 1.53398078788564122971e-3f   // (pi/2)/1024

// All-VALU (DPP) reduction over the 8 lanes differing in bits 0..2.
__device__ __forceinline__ float red8_dpp(float x) {
    x += __int_as_float(__builtin_amdgcn_mov_dpp(__float_as_int(x), 0xB1, 0xF, 0xF, true));
    x += __int_as_float(__builtin_amdgcn_mov_dpp(__float_as_int(x), 0x4E, 0xF, 0xF, true));
    x += __int_as_float(__builtin_amdgcn_mov_dpp(__float_as_int(x), 0x141, 0xF, 0xF, true));
    return x;
}

// XCD-affinity decode (512 blocks, round-robin dispatch puts bid%8 on XCD
// bid%8): head n lives entirely on XCD n&7 across ALL THREE kernels, so the
// sumkv panel (1 MB/head, 2 MB/XCD < 4 MB L2) never leaves its XCD between
// K1-write, K2-scan, and K3-read.
__device__ __forceinline__ void decode_cn(int bid, int& c, int& n) {
    int xcd = bid & 7, slot = bid >> 3;      // slot 0..63
    n = xcd + ((slot & 1) << 3);             // heads {xcd, xcd+8}
    c = slot >> 1;                           // chunk / slice 0..31
}

// ---------------------------------------------------------------------------
// K1: per-(chunk, head) local sums (raw). 256 threads; thread owns 16
// d2-cols (g = tid&7) x 2 m-cols. Body identical to round-2 best.
// ---------------------------------------------------------------------------
__global__ __launch_bounds__(256, 2) void k1_chunk_sums(
    const float* __restrict__ k, const float* __restrict__ v,
    float* __restrict__ sumkv, float* __restrict__ sumk)
{
    __shared__ __attribute__((aligned(16))) float k_s[T_CHUNK][ROWP];
    __shared__ __attribute__((aligned(16))) float v_s[T_CHUNK][D_HEAD];
    __shared__ float s_tab[T_CHUNK], c_tab[T_CHUNK];

    int c, n; decode_cn(blockIdx.x, c, n);
    const int tid = threadIdx.x;
    const int base = (n * L_SEQ + c * T_CHUNK) * D_HEAD;

    if (tid < T_CHUNK) {
        float th = SINCOS_SCALE * (float)(c * T_CHUNK + tid + 1);
        s_tab[tid] = __sinf(th);
        c_tab[tid] = __cosf(th);
    }
    __syncthreads();

    const float4* k4g = (const float4*)(k + base);
    const float4* v4g = (const float4*)(v + base);
#pragma unroll
    for (int j = 0; j < 2; ++j) {
        int i4 = j * 256 + tid;            // 0..511
        int l = i4 >> 4, d = (i4 & 15) << 2;
        float4 kk = k4g[i4], vv = v4g[i4];
        kk.x = fmaxf(kk.x, 0.f); kk.y = fmaxf(kk.y, 0.f);
        kk.z = fmaxf(kk.z, 0.f); kk.w = fmaxf(kk.w, 0.f);
        vv.x = fmaxf(vv.x, 0.f); vv.y = fmaxf(vv.y, 0.f);
        vv.z = fmaxf(vv.z, 0.f); vv.w = fmaxf(vv.w, 0.f);
        float s = s_tab[l], cs = c_tab[l];
        *(float4*)&k_s[l][pad_col(d)]      = make_float4(kk.x*s,  kk.y*s,  kk.z*s,  kk.w*s);
        *(float4*)&k_s[l][pad_col(d + 64)] = make_float4(kk.x*cs, kk.y*cs, kk.z*cs, kk.w*cs);
        *(float4*)&v_s[l][d] = vv;
    }
    __syncthreads();

    // Column sums of k_ -> sumk (raw per-chunk), computed once.
    if (tid < D2) {
        int pc = pad_col(tid);
        float ks = 0.f;
#pragma unroll
        for (int l = 0; l < T_CHUNK; ++l) ks += k_s[l][pc];
        sumk[(n * N_CHUNK + c) * D2 + tid] = ks;
    }

    const int g = tid & 7, mh = (tid >> 3) << 1;
    const int gbase = pad_col(16 * g);

    float st0[16], st1[16];
#pragma unroll
    for (int j = 0; j < 16; ++j) { st0[j] = 0.f; st1[j] = 0.f; }

    for (int l = 0; l < T_CHUNK; ++l) {
        float2 vm = *(const float2*)&v_s[l][mh];
        const float4* kv4 = (const float4*)&k_s[l][gbase];
#pragma unroll
        for (int jj = 0; jj < 4; ++jj) {
            float4 kk = kv4[jj];
            st0[4*jj+0] = fmaf(kk.x, vm.x, st0[4*jj+0]);
            st1[4*jj+0] = fmaf(kk.x, vm.y, st1[4*jj+0]);
            st0[4*jj+1] = fmaf(kk.y, vm.x, st0[4*jj+1]);
            st1[4*jj+1] = fmaf(kk.y, vm.y, st1[4*jj+1]);
            st0[4*jj+2] = fmaf(kk.z, vm.x, st0[4*jj+2]);
            st1[4*jj+2] = fmaf(kk.z, vm.y, st1[4*jj+2]);
            st0[4*jj+3] = fmaf(kk.w, vm.x, st0[4*jj+3]);
            st1[4*jj+3] = fmaf(kk.w, vm.y, st1[4*jj+3]);
        }
    }

    // Coalesced float4 stores, thread-interleaved flat layout (K3 mirrors it).
    float4* dst = (float4*)(sumkv + (size_t)(n * N_CHUNK + c) * KV_ELEMS);
#pragma unroll
    for (int j4 = 0; j4 < 4; ++j4) {
        dst[(2*j4+0)*256 + tid] = make_float4(st0[4*j4], st0[4*j4+1], st0[4*j4+2], st0[4*j4+3]);
        dst[(2*j4+1)*256 + tid] = make_float4(st1[4*j4], st1[4*j4+1], st1[4*j4+2], st1[4*j4+3]);
    }
}

// ---------------------------------------------------------------------------
// K2: exclusive prefix over chunks of sumkv only (sumk scan folded into K3).
// XCD-affine: slice blocks of head n run on the XCD holding head n's panel,
// so all 32 stride-32KB loads/stores are L2 hits.
// ---------------------------------------------------------------------------
__global__ __launch_bounds__(256) void k2_prefix(float* __restrict__ sumkv)
{
    int s, n; decode_cn(blockIdx.x, s, n);   // s = element slice 0..31
    const int tid = threadIdx.x;

    float* base = sumkv + (size_t)n * N_CHUNK * KV_ELEMS + s * 256 + tid;
    float t[N_CHUNK];
#pragma unroll
    for (int c = 0; c < N_CHUNK; ++c) t[c] = base[c * KV_ELEMS];
    float r = 0.f;
#pragma unroll
    for (int c = 0; c < N_CHUNK; ++c) { base[c * KV_ELEMS] = r; r += t[c]; }
}

// ---------------------------------------------------------------------------
// K3: outputs. Body identical to round-2 best; sumk exclusive prefix
// computed in-block (<=31 L2-local scalar loads by 128 threads).
// ---------------------------------------------------------------------------
__global__ __launch_bounds__(256, 2) void k3_output(
    const float* __restrict__ q, const float* __restrict__ k,
    const float* __restrict__ v, const float* __restrict__ sumkv,
    const float* __restrict__ sumk, float* __restrict__ out)
{
    __shared__ __attribute__((aligned(16))) float k_s[T_CHUNK][ROWP];
    __shared__ __attribute__((aligned(16))) float q_s[T_CHUNK][ROWP];
    __shared__ __attribute__((aligned(16))) float v_s[T_CHUNK][D_HEAD];
    __shared__ __attribute__((aligned(16))) float pool[T_CHUNK * PARTP]; // part_s / out_s
    __shared__ float rden_s[T_CHUNK];
    __shared__ float s_tab[T_CHUNK], c_tab[T_CHUNK];

    float (*part_s)[PARTP] = (float(*)[PARTP])pool;
    float (*out_s)[D_HEAD] = (float(*)[D_HEAD])pool;

    int c, n; decode_cn(blockIdx.x, c, n);
    const int tid = threadIdx.x;
    const int base = (n * L_SEQ + c * T_CHUNK) * D_HEAD;

    if (tid < T_CHUNK) {
        float th = SINCOS_SCALE * (float)(c * T_CHUNK + tid + 1);
        s_tab[tid] = __sinf(th);
        c_tab[tid] = __cosf(th);
    }
    __syncthreads();

    const float4* q4g = (const float4*)(q + base);
    const float4* k4g = (const float4*)(k + base);
    const float4* v4g = (const float4*)(v + base);
#pragma unroll
    for (int j = 0; j < 2; ++j) {
        int i4 = j * 256 + tid;
        int l = i4 >> 4, d = (i4 & 15) << 2;
        float4 kk = k4g[i4], qq = q4g[i4], vv = v4g[i4];
        kk.x = fmaxf(kk.x, 0.f); kk.y = fmaxf(kk.y, 0.f);
        kk.z = fmaxf(kk.z, 0.f); kk.w = fmaxf(kk.w, 0.f);
        qq.x = fmaxf(qq.x, 0.f); qq.y = fmaxf(qq.y, 0.f);
        qq.z = fmaxf(qq.z, 0.f); qq.w = fmaxf(qq.w, 0.f);
        vv.x = fmaxf(vv.x, 0.f); vv.y = fmaxf(vv.y, 0.f);
        vv.z = fmaxf(vv.z, 0.f); vv.w = fmaxf(vv.w, 0.f);
        float s = s_tab[l], cs = c_tab[l];
        *(float4*)&k_s[l][pad_col(d)]      = make_float4(kk.x*s,  kk.y*s,  kk.z*s,  kk.w*s);
        *(float4*)&k_s[l][pad_col(d + 64)] = make_float4(kk.x*cs, kk.y*cs, kk.z*cs, kk.w*cs);
        *(float4*)&q_s[l][pad_col(d)]      = make_float4(qq.x*s,  qq.y*s,  qq.z*s,  qq.w*s);
        *(float4*)&q_s[l][pad_col(d + 64)] = make_float4(qq.x*cs, qq.y*cs, qq.z*cs, qq.w*cs);
        *(float4*)&v_s[l][d] = vv;
    }

    // Prefix state loads issued before the barrier (latency overlap);
    // L2-local thanks to the affinity chain.
    const float4* pkv = (const float4*)(sumkv + (size_t)(n * N_CHUNK + c) * KV_ELEMS);
    float st0[16], st1[16];
#pragma unroll
    for (int i = 0; i < 4; ++i) {
        float4 p0 = pkv[(2*i+0) * 256 + tid];
        float4 p1 = pkv[(2*i+1) * 256 + tid];
        st0[4*i+0] = p0.x; st0[4*i+1] = p0.y; st0[4*i+2] = p0.z; st0[4*i+3] = p0.w;
        st1[4*i+0] = p1.x; st1[4*i+1] = p1.y; st1[4*i+2] = p1.z; st1[4*i+3] = p1.w;
    }

    // sumk exclusive prefix for this chunk (tid<128), 4-way unrolled.
    float kc = 0.f;
    if (tid < D2) {
        const float* bk = sumk + (size_t)n * N_CHUNK * D2 + tid;
        float k0 = 0.f, k1 = 0.f, k2 = 0.f, k3 = 0.f;
        int cc = 0;
        for (; cc + 4 <= c; cc += 4) {
            k0 += bk[(cc+0) * D2]; k1 += bk[(cc+1) * D2];
            k2 += bk[(cc+2) * D2]; k3 += bk[(cc+3) * D2];
        }
        for (; cc < c; ++cc) k0 += bk[cc * D2];
        kc = (k0 + k1) + (k2 + k3);
    }

    __syncthreads();

    // Denominator: per-column running k-cumsum * q, once per block.
    if (tid < D2) {
        int pc = pad_col(tid);
#pragma unroll
        for (int l = 0; l < T_CHUNK; ++l) {
            kc += k_s[l][pc];
            part_s[l][tid] = q_s[l][pc] * kc;
        }
    }
    __syncthreads();

    {
        int l = tid >> 3, j = tid & 7;
        const float4* p4 = (const float4*)&part_s[l][j * 16];
        float4 aa = p4[0], bb = p4[1], cc4 = p4[2], dd = p4[3];
        float sum = ((aa.x + aa.y) + (aa.z + aa.w)) + ((bb.x + bb.y) + (bb.z + bb.w))
                  + ((cc4.x + cc4.y) + (cc4.z + cc4.w)) + ((dd.x + dd.y) + (dd.z + dd.w));
        sum = red8_dpp(sum);
        if (j == 0) rden_s[l] = 1.f / fmaxf(sum, 1e-6f);
    }
    __syncthreads();   // part_s dead; pool becomes out_s

    const int g = tid & 7, mh = (tid >> 3) << 1;
    const int gbase = pad_col(16 * g);

    for (int l = 0; l < T_CHUNK; ++l) {
        float2 vm = *(const float2*)&v_s[l][mh];
        const float4* kv4 = (const float4*)&k_s[l][gbase];
        const float4* qv4 = (const float4*)&q_s[l][gbase];
        float a0 = 0.f, a1 = 0.f;
#pragma unroll
        for (int jj = 0; jj < 4; ++jj) {
            float4 kk = kv4[jj];
            float4 qq = qv4[jj];
            st0[4*jj+0] = fmaf(kk.x, vm.x, st0[4*jj+0]); a0 = fmaf(qq.x, st0[4*jj+0], a0);
            st1[4*jj+0] = fmaf(kk.x, vm.y, st1[4*jj+0]); a1 = fmaf(qq.x, st1[4*jj+0], a1);
            st0[4*jj+1] = fmaf(kk.y, vm.x, st0[4*jj+1]); a0 = fmaf(qq.y, st0[4*jj+1], a0);
            st1[4*jj+1] = fmaf(kk.y, vm.y, st1[4*jj+1]); a1 = fmaf(qq.y, st1[4*jj+1], a1);
            st0[4*jj+2] = fmaf(kk.z, vm.x, st0[4*jj+2]); a0 = fmaf(qq.z, st0[4*jj+2], a0);
            st1[4*jj+2] = fmaf(kk.z, vm.y, st1[4*jj+2]); a1 = fmaf(qq.z, st1[4*jj+2], a1);
            st0[4*jj+3] = fmaf(kk.w, vm.x, st0[4*jj+3]); a0 = fmaf(qq.w, st0[4*jj+3], a0);
            st1[4*jj+3] = fmaf(kk.w, vm.y, st1[4*jj+3]); a1 = fmaf(qq.w, st1[4*jj+3], a1);
        }
        a0 = red8_dpp(a0);
        a1 = red8_dpp(a1);
        if (g == 0) {
            float r = rden_s[l];
            *(float2*)&out_s[l][mh] = make_float2(a0 * r, a1 * r);
        }
    }
    __syncthreads();

    // Coalesced output store.
    {
        float4* o4 = (float4*)(out + base);
        const float4* s4o = (const float4*)&out_s[0][0];
        o4[tid] = s4o[tid];
        o4[256 + tid] = s4o[256 + tid];
    }
}

// ---------------------------------------------------------------------------
extern "C" void kernel_launch(void* const* d_in, const int* in_sizes, int n_in,
                              void* d_out, int out_size, void* d_ws, size_t ws_size,
                              hipStream_t stream) {
    (void)in_sizes; (void)n_in; (void)out_size; (void)ws_size;
    const float* q = (const float*)d_in[0];
    const float* k = (const float*)d_in[1];
    const float* v = (const float*)d_in[2];
    float* out = (float*)d_out;

    float* sumkv = (float*)d_ws;                                   // [N][C][8192] flat
    float* sumk  = sumkv + (size_t)N_HEADS * N_CHUNK * KV_ELEMS;   // [N][C][128]

    k1_chunk_sums<<<dim3(N_CHUNK * N_HEADS), 256, 0, stream>>>(k, v, sumkv, sumk);
    k2_prefix<<<dim3(N_CHUNK * N_HEADS), 256, 0, stream>>>(sumkv);
    k3_output<<<dim3(N_CHUNK * N_HEADS), 256, 0, stream>>>(q, k, v, sumkv, sumk, out);
}

// Round 9
// 87.408 us; speedup vs baseline: 1.1827x; 1.1070x over previous
//
#include <hip/hip_runtime.h>
#include <hip/hip_fp16.h>

// Problem constants (B=2, H=8, L=1024, D=64)
#define N_HEADS 16          // B*H
#define L_SEQ   1024
#define D_HEAD  64
#define D2      128         // 2*D (sin/cos concat)
#define T_CHUNK 32
#define N_CHUNK (L_SEQ / T_CHUNK)   // 32
#define KV_ELEMS (D2 * D_HEAD)      // 8192 f32 values per chunk
#define PK_UINTS (KV_ELEMS / 2)     // 4096 packed half2 per chunk

// Padded LDS row: +4 floats every 32 cols; g-group b128 reads land 2-way max.
#define ROWP 140
#define PARTP 132

__device__ __forceinline__ int pad_col(int d2) { return d2 + 4 * (d2 >> 5); }

#define SINCOS_SCALE 1.53398078788564122971e-3f   // (pi/2)/1024

// f16 pack/unpack (RNE). Scan accumulation stays f32; only storage is f16.
__device__ __forceinline__ unsigned int packh2(float a, float b) {
    __half2 h = __floats2half2_rn(a, b);
    return __builtin_bit_cast(unsigned int, h);
}
__device__ __forceinline__ float2 unpackh2(unsigned int u) {
    __half2 h = __builtin_bit_cast(__half2, u);
    return __half22float2(h);
}

// All-VALU (DPP) reduction over the 8 lanes differing in bits 0..2.
__device__ __forceinline__ float red8_dpp(float x) {
    x += __int_as_float(__builtin_amdgcn_mov_dpp(__float_as_int(x), 0xB1, 0xF, 0xF, true));
    x += __int_as_float(__builtin_amdgcn_mov_dpp(__float_as_int(x), 0x4E, 0xF, 0xF, true));
    x += __int_as_float(__builtin_amdgcn_mov_dpp(__float_as_int(x), 0x141, 0xF, 0xF, true));
    return x;
}

// ---------------------------------------------------------------------------
// K1: per-(chunk, head) local sums. Round-2 body; output packed f16.
// ---------------------------------------------------------------------------
__global__ __launch_bounds__(256, 2) void k1_chunk_sums(
    const float* __restrict__ k, const float* __restrict__ v,
    unsigned int* __restrict__ sumkv, float* __restrict__ sumk)
{
    __shared__ __attribute__((aligned(16))) float k_s[T_CHUNK][ROWP];
    __shared__ __attribute__((aligned(16))) float v_s[T_CHUNK][D_HEAD];
    __shared__ float s_tab[T_CHUNK], c_tab[T_CHUNK];

    const int c = blockIdx.x, n = blockIdx.y;
    const int tid = threadIdx.x;
    const int base = (n * L_SEQ + c * T_CHUNK) * D_HEAD;

    if (tid < T_CHUNK) {
        float th = SINCOS_SCALE * (float)(c * T_CHUNK + tid + 1);
        s_tab[tid] = __sinf(th);
        c_tab[tid] = __cosf(th);
    }
    __syncthreads();

    const float4* k4g = (const float4*)(k + base);
    const float4* v4g = (const float4*)(v + base);
#pragma unroll
    for (int j = 0; j < 2; ++j) {
        int i4 = j * 256 + tid;            // 0..511
        int l = i4 >> 4, d = (i4 & 15) << 2;
        float4 kk = k4g[i4], vv = v4g[i4];
        kk.x = fmaxf(kk.x, 0.f); kk.y = fmaxf(kk.y, 0.f);
        kk.z = fmaxf(kk.z, 0.f); kk.w = fmaxf(kk.w, 0.f);
        vv.x = fmaxf(vv.x, 0.f); vv.y = fmaxf(vv.y, 0.f);
        vv.z = fmaxf(vv.z, 0.f); vv.w = fmaxf(vv.w, 0.f);
        float s = s_tab[l], cs = c_tab[l];
        *(float4*)&k_s[l][pad_col(d)]      = make_float4(kk.x*s,  kk.y*s,  kk.z*s,  kk.w*s);
        *(float4*)&k_s[l][pad_col(d + 64)] = make_float4(kk.x*cs, kk.y*cs, kk.z*cs, kk.w*cs);
        *(float4*)&v_s[l][d] = vv;
    }
    __syncthreads();

    // Column sums of k_ -> sumk (f32, tiny), computed once.
    if (tid < D2) {
        int pc = pad_col(tid);
        float ks = 0.f;
#pragma unroll
        for (int l = 0; l < T_CHUNK; ++l) ks += k_s[l][pc];
        sumk[(n * N_CHUNK + c) * D2 + tid] = ks;
    }

    const int g = tid & 7, mh = (tid >> 3) << 1;
    const int gbase = pad_col(16 * g);

    float st0[16], st1[16];
#pragma unroll
    for (int j = 0; j < 16; ++j) { st0[j] = 0.f; st1[j] = 0.f; }

    for (int l = 0; l < T_CHUNK; ++l) {
        float2 vm = *(const float2*)&v_s[l][mh];
        const float4* kv4 = (const float4*)&k_s[l][gbase];
#pragma unroll
        for (int jj = 0; jj < 4; ++jj) {
            float4 kk = kv4[jj];
            st0[4*jj+0] = fmaf(kk.x, vm.x, st0[4*jj+0]);
            st1[4*jj+0] = fmaf(kk.x, vm.y, st1[4*jj+0]);
            st0[4*jj+1] = fmaf(kk.y, vm.x, st0[4*jj+1]);
            st1[4*jj+1] = fmaf(kk.y, vm.y, st1[4*jj+1]);
            st0[4*jj+2] = fmaf(kk.z, vm.x, st0[4*jj+2]);
            st1[4*jj+2] = fmaf(kk.z, vm.y, st1[4*jj+2]);
            st0[4*jj+3] = fmaf(kk.w, vm.x, st0[4*jj+3]);
            st1[4*jj+3] = fmaf(kk.w, vm.y, st1[4*jj+3]);
        }
    }

    // Packed f16 stores: 4x uint4 per thread, thread-interleaved (K3 mirrors).
    uint4* dst = (uint4*)(sumkv + (size_t)(n * N_CHUNK + c) * PK_UINTS);
    dst[0*256 + tid] = make_uint4(packh2(st0[0],st0[1]),  packh2(st0[2],st0[3]),
                                  packh2(st0[4],st0[5]),  packh2(st0[6],st0[7]));
    dst[1*256 + tid] = make_uint4(packh2(st0[8],st0[9]),  packh2(st0[10],st0[11]),
                                  packh2(st0[12],st0[13]),packh2(st0[14],st0[15]));
    dst[2*256 + tid] = make_uint4(packh2(st1[0],st1[1]),  packh2(st1[2],st1[3]),
                                  packh2(st1[4],st1[5]),  packh2(st1[6],st1[7]));
    dst[3*256 + tid] = make_uint4(packh2(st1[8],st1[9]),  packh2(st1[10],st1[11]),
                                  packh2(st1[12],st1[13]),packh2(st1[14],st1[15]));
}

// ---------------------------------------------------------------------------
// K2: exclusive prefix over chunks. Packed f16 storage, f32 accumulation.
// uint2 (4 f16) per thread, fully unrolled 32-deep load pipeline.
// ---------------------------------------------------------------------------
__global__ __launch_bounds__(256) void k2_prefix(
    unsigned int* __restrict__ sumkv, float* __restrict__ sumk)
{
    const int x = blockIdx.x, n = blockIdx.y;
    const int tid = threadIdx.x;

    if (x < 8) {
        uint2* base = (uint2*)(sumkv + (size_t)n * N_CHUNK * PK_UINTS) + x * 256 + tid;
        uint2 t[N_CHUNK];
#pragma unroll
        for (int c = 0; c < N_CHUNK; ++c) t[c] = base[c * (PK_UINTS / 2)];
        float r0 = 0.f, r1 = 0.f, r2 = 0.f, r3 = 0.f;
#pragma unroll
        for (int c = 0; c < N_CHUNK; ++c) {
            uint2 cur = t[c];
            base[c * (PK_UINTS / 2)] = make_uint2(packh2(r0, r1), packh2(r2, r3));
            float2 lo = unpackh2(cur.x), hi = unpackh2(cur.y);
            r0 += lo.x; r1 += lo.y; r2 += hi.x; r3 += hi.y;
        }
    } else if (tid < D2) {
        float* bk = sumk + n * N_CHUNK * D2 + tid;
        float t[N_CHUNK];
#pragma unroll
        for (int c = 0; c < N_CHUNK; ++c) t[c] = bk[c * D2];
        float r = 0.f;
#pragma unroll
        for (int c = 0; c < N_CHUNK; ++c) { bk[c * D2] = r; r += t[c]; }
    }
}

// ---------------------------------------------------------------------------
// K3: outputs. Round-2 body; prefix state loaded packed f16, f32 compute.
// ---------------------------------------------------------------------------
__global__ __launch_bounds__(256, 2) void k3_output(
    const float* __restrict__ q, const float* __restrict__ k,
    const float* __restrict__ v, const unsigned int* __restrict__ sumkv,
    const float* __restrict__ sumk, float* __restrict__ out)
{
    __shared__ __attribute__((aligned(16))) float k_s[T_CHUNK][ROWP];
    __shared__ __attribute__((aligned(16))) float q_s[T_CHUNK][ROWP];
    __shared__ __attribute__((aligned(16))) float v_s[T_CHUNK][D_HEAD];
    __shared__ __attribute__((aligned(16))) float pool[T_CHUNK * PARTP]; // part_s / out_s
    __shared__ float rden_s[T_CHUNK];
    __shared__ float s_tab[T_CHUNK], c_tab[T_CHUNK];

    float (*part_s)[PARTP] = (float(*)[PARTP])pool;
    float (*out_s)[D_HEAD] = (float(*)[D_HEAD])pool;

    const int c = blockIdx.x, n = blockIdx.y;
    const int tid = threadIdx.x;
    const int base = (n * L_SEQ + c * T_CHUNK) * D_HEAD;

    if (tid < T_CHUNK) {
        float th = SINCOS_SCALE * (float)(c * T_CHUNK + tid + 1);
        s_tab[tid] = __sinf(th);
        c_tab[tid] = __cosf(th);
    }
    __syncthreads();

    const float4* q4g = (const float4*)(q + base);
    const float4* k4g = (const float4*)(k + base);
    const float4* v4g = (const float4*)(v + base);
#pragma unroll
    for (int j = 0; j < 2; ++j) {
        int i4 = j * 256 + tid;
        int l = i4 >> 4, d = (i4 & 15) << 2;
        float4 kk = k4g[i4], qq = q4g[i4], vv = v4g[i4];
        kk.x = fmaxf(kk.x, 0.f); kk.y = fmaxf(kk.y, 0.f);
        kk.z = fmaxf(kk.z, 0.f); kk.w = fmaxf(kk.w, 0.f);
        qq.x = fmaxf(qq.x, 0.f); qq.y = fmaxf(qq.y, 0.f);
        qq.z = fmaxf(qq.z, 0.f); qq.w = fmaxf(qq.w, 0.f);
        vv.x = fmaxf(vv.x, 0.f); vv.y = fmaxf(vv.y, 0.f);
        vv.z = fmaxf(vv.z, 0.f); vv.w = fmaxf(vv.w, 0.f);
        float s = s_tab[l], cs = c_tab[l];
        *(float4*)&k_s[l][pad_col(d)]      = make_float4(kk.x*s,  kk.y*s,  kk.z*s,  kk.w*s);
        *(float4*)&k_s[l][pad_col(d + 64)] = make_float4(kk.x*cs, kk.y*cs, kk.z*cs, kk.w*cs);
        *(float4*)&q_s[l][pad_col(d)]      = make_float4(qq.x*s,  qq.y*s,  qq.z*s,  qq.w*s);
        *(float4*)&q_s[l][pad_col(d + 64)] = make_float4(qq.x*cs, qq.y*cs, qq.z*cs, qq.w*cs);
        *(float4*)&v_s[l][d] = vv;
    }

    // Packed prefix-state loads issued before the barrier (latency overlap).
    const uint4* pkv = (const uint4*)(sumkv + (size_t)(n * N_CHUNK + c) * PK_UINTS);
    uint4 p0 = pkv[0*256 + tid];
    uint4 p1 = pkv[1*256 + tid];
    uint4 p2 = pkv[2*256 + tid];
    uint4 p3 = pkv[3*256 + tid];
    float kc = 0.f;
    if (tid < D2) kc = sumk[(n * N_CHUNK + c) * D2 + tid];

    float st0[16], st1[16];
    {
        float2 f;
        f = unpackh2(p0.x); st0[0]=f.x;  st0[1]=f.y;
        f = unpackh2(p0.y); st0[2]=f.x;  st0[3]=f.y;
        f = unpackh2(p0.z); st0[4]=f.x;  st0[5]=f.y;
        f = unpackh2(p0.w); st0[6]=f.x;  st0[7]=f.y;
        f = unpackh2(p1.x); st0[8]=f.x;  st0[9]=f.y;
        f = unpackh2(p1.y); st0[10]=f.x; st0[11]=f.y;
        f = unpackh2(p1.z); st0[12]=f.x; st0[13]=f.y;
        f = unpackh2(p1.w); st0[14]=f.x; st0[15]=f.y;
        f = unpackh2(p2.x); st1[0]=f.x;  st1[1]=f.y;
        f = unpackh2(p2.y); st1[2]=f.x;  st1[3]=f.y;
        f = unpackh2(p2.z); st1[4]=f.x;  st1[5]=f.y;
        f = unpackh2(p2.w); st1[6]=f.x;  st1[7]=f.y;
        f = unpackh2(p3.x); st1[8]=f.x;  st1[9]=f.y;
        f = unpackh2(p3.y); st1[10]=f.x; st1[11]=f.y;
        f = unpackh2(p3.z); st1[12]=f.x; st1[13]=f.y;
        f = unpackh2(p3.w); st1[14]=f.x; st1[15]=f.y;
    }

    __syncthreads();

    // Denominator: per-column running k-cumsum * q, once per block (f32).
    if (tid < D2) {
        int pc = pad_col(tid);
#pragma unroll
        for (int l = 0; l < T_CHUNK; ++l) {
            kc += k_s[l][pc];
            part_s[l][tid] = q_s[l][pc] * kc;
        }
    }
    __syncthreads();

    {
        int l = tid >> 3, j = tid & 7;
        const float4* p4 = (const float4*)&part_s[l][j * 16];
        float4 aa = p4[0], bb = p4[1], cc4 = p4[2], dd = p4[3];
        float sum = ((aa.x + aa.y) + (aa.z + aa.w)) + ((bb.x + bb.y) + (bb.z + bb.w))
                  + ((cc4.x + cc4.y) + (cc4.z + cc4.w)) + ((dd.x + dd.y) + (dd.z + dd.w));
        sum = red8_dpp(sum);
        if (j == 0) rden_s[l] = 1.f / fmaxf(sum, 1e-6f);
    }
    __syncthreads();   // part_s dead; pool becomes out_s

    const int g = tid & 7, mh = (tid >> 3) << 1;
    const int gbase = pad_col(16 * g);

    for (int l = 0; l < T_CHUNK; ++l) {
        float2 vm = *(const float2*)&v_s[l][mh];
        const float4* kv4 = (const float4*)&k_s[l][gbase];
        const float4* qv4 = (const float4*)&q_s[l][gbase];
        float a0 = 0.f, a1 = 0.f;
#pragma unroll
        for (int jj = 0; jj < 4; ++jj) {
            float4 kk = kv4[jj];
            float4 qq = qv4[jj];
            st0[4*jj+0] = fmaf(kk.x, vm.x, st0[4*jj+0]); a0 = fmaf(qq.x, st0[4*jj+0], a0);
            st1[4*jj+0] = fmaf(kk.x, vm.y, st1[4*jj+0]); a1 = fmaf(qq.x, st1[4*jj+0], a1);
            st0[4*jj+1] = fmaf(kk.y, vm.x, st0[4*jj+1]); a0 = fmaf(qq.y, st0[4*jj+1], a0);
            st1[4*jj+1] = fmaf(kk.y, vm.y, st1[4*jj+1]); a1 = fmaf(qq.y, st1[4*jj+1], a1);
            st0[4*jj+2] = fmaf(kk.z, vm.x, st0[4*jj+2]); a0 = fmaf(qq.z, st0[4*jj+2], a0);
            st1[4*jj+2] = fmaf(kk.z, vm.y, st1[4*jj+2]); a1 = fmaf(qq.z, st1[4*jj+2], a1);
            st0[4*jj+3] = fmaf(kk.w, vm.x, st0[4*jj+3]); a0 = fmaf(qq.w, st0[4*jj+3], a0);
            st1[4*jj+3] = fmaf(kk.w, vm.y, st1[4*jj+3]); a1 = fmaf(qq.w, st1[4*jj+3], a1);
        }
        a0 = red8_dpp(a0);
        a1 = red8_dpp(a1);
        if (g == 0) {
            float r = rden_s[l];
            *(float2*)&out_s[l][mh] = make_float2(a0 * r, a1 * r);
        }
    }
    __syncthreads();

    // Coalesced output store.
    {
        float4* o4 = (float4*)(out + base);
        const float4* s4o = (const float4*)&out_s[0][0];
        o4[tid] = s4o[tid];
        o4[256 + tid] = s4o[256 + tid];
    }
}

// ---------------------------------------------------------------------------
extern "C" void kernel_launch(void* const* d_in, const int* in_sizes, int n_in,
                              void* d_out, int out_size, void* d_ws, size_t ws_size,
                              hipStream_t stream) {
    (void)in_sizes; (void)n_in; (void)out_size; (void)ws_size;
    const float* q = (const float*)d_in[0];
    const float* k = (const float*)d_in[1];
    const float* v = (const float*)d_in[2];
    float* out = (float*)d_out;

    unsigned int* sumkv = (unsigned int*)d_ws;                         // packed f16 [N][C][4096]
    float* sumk = (float*)(sumkv + (size_t)N_HEADS * N_CHUNK * PK_UINTS); // f32 [N][C][128]

    dim3 grid(N_CHUNK, N_HEADS);
    k1_chunk_sums<<<grid, 256, 0, stream>>>(k, v, sumkv, sumk);
    dim3 grid2(9, N_HEADS);
    k2_prefix<<<grid2, 256, 0, stream>>>(sumkv, sumk);
    k3_output<<<grid, 256, 0, stream>>>(q, k, v, sumkv, sumk, out);
}

// Round 11
// 79.031 us; speedup vs baseline: 1.3080x; 1.1060x over previous
//
#include <hip/hip_runtime.h>
#include <hip/hip_fp16.h>

// Problem constants (B=2, H=8, L=1024, D=64)
#define N_HEADS 16          // B*H
#define L_SEQ   1024
#define D_HEAD  64
#define D2      128         // 2*D (sin/cos concat)
#define T_CHUNK 32
#define N_CHUNK (L_SEQ / T_CHUNK)   // 32
#define KV_ELEMS (D2 * D_HEAD)      // 8192 f16 values per chunk
#define PK_UINTS (KV_ELEMS / 2)     // 4096 packed half2 per chunk

// f32 padded LDS row for K1 (unchanged proven body)
#define ROWP 140
__device__ __forceinline__ int pad_col(int d2) { return d2 + 4 * (d2 >> 5); }

// f16 LDS pitches (elements), chosen for 2-way-max bank aliasing on
// the 16-lane fragment reads and 8/16B alignment:
#define PQ 132   // q16/k16 [32][PQ]   (stride 264B -> (2i)%32, conflict-free)
#define PS 136   // s0t     [64][PS]   (stride 272B -> (4i)%32, 2-way = free)
#define PV 36    // vt[64], pmat[32]   (stride 72B  -> (18i)%32, conflict-free)

#define SINCOS_SCALE 1.53398078788564122971e-3f   // (pi/2)/1024

typedef _Float16 f16_t;
typedef __attribute__((ext_vector_type(4))) _Float16 f16x4;
typedef __attribute__((ext_vector_type(4))) float f32x4;

__device__ __forceinline__ f32x4 mfma16(f16x4 a, f16x4 b, f32x4 c) {
    return __builtin_amdgcn_mfma_f32_16x16x16f16(a, b, c, 0, 0, 0);
}

// f16 pack helpers (storage only; accumulation stays f32)
__device__ __forceinline__ unsigned int packh2(float a, float b) {
    __half2 h = __floats2half2_rn(a, b);
    return __builtin_bit_cast(unsigned int, h);
}
__device__ __forceinline__ float2 unpackh2(unsigned int u) {
    __half2 h = __builtin_bit_cast(__half2, u);
    return __half22float2(h);
}

// All-VALU (DPP) reductions.
__device__ __forceinline__ float red8_dpp(float x) {
    x += __int_as_float(__builtin_amdgcn_mov_dpp(__float_as_int(x), 0xB1, 0xF, 0xF, true));
    x += __int_as_float(__builtin_amdgcn_mov_dpp(__float_as_int(x), 0x4E, 0xF, 0xF, true));
    x += __int_as_float(__builtin_amdgcn_mov_dpp(__float_as_int(x), 0x141, 0xF, 0xF, true));
    return x;
}
__device__ __forceinline__ float red16_dpp(float x) {
    x += __int_as_float(__builtin_amdgcn_mov_dpp(__float_as_int(x), 0xB1, 0xF, 0xF, true));
    x += __int_as_float(__builtin_amdgcn_mov_dpp(__float_as_int(x), 0x4E, 0xF, 0xF, true));
    x += __int_as_float(__builtin_amdgcn_mov_dpp(__float_as_int(x), 0x141, 0xF, 0xF, true));
    x += __int_as_float(__builtin_amdgcn_mov_dpp(__float_as_int(x), 0x140, 0xF, 0xF, true));
    return x;
}

// ---------------------------------------------------------------------------
// K1: per-(chunk, head) local sums. Proven R9 VALU body; store layout changed
// to packed-f16 [m][d2] so K3 can consume the scanned state as an MFMA
// B-operand (S0^T rows) directly.
// ---------------------------------------------------------------------------
__global__ __launch_bounds__(256, 2) void k1_chunk_sums(
    const float* __restrict__ k, const float* __restrict__ v,
    unsigned int* __restrict__ sumkv, float* __restrict__ sumk)
{
    __shared__ __attribute__((aligned(16))) float k_s[T_CHUNK][ROWP];
    __shared__ __attribute__((aligned(16))) float v_s[T_CHUNK][D_HEAD];
    __shared__ float s_tab[T_CHUNK], c_tab[T_CHUNK];

    const int c = blockIdx.x, n = blockIdx.y;
    const int tid = threadIdx.x;
    const int base = (n * L_SEQ + c * T_CHUNK) * D_HEAD;

    if (tid < T_CHUNK) {
        float th = SINCOS_SCALE * (float)(c * T_CHUNK + tid + 1);
        s_tab[tid] = __sinf(th);
        c_tab[tid] = __cosf(th);
    }
    __syncthreads();

    const float4* k4g = (const float4*)(k + base);
    const float4* v4g = (const float4*)(v + base);
#pragma unroll
    for (int j = 0; j < 2; ++j) {
        int i4 = j * 256 + tid;            // 0..511
        int l = i4 >> 4, d = (i4 & 15) << 2;
        float4 kk = k4g[i4], vv = v4g[i4];
        kk.x = fmaxf(kk.x, 0.f); kk.y = fmaxf(kk.y, 0.f);
        kk.z = fmaxf(kk.z, 0.f); kk.w = fmaxf(kk.w, 0.f);
        vv.x = fmaxf(vv.x, 0.f); vv.y = fmaxf(vv.y, 0.f);
        vv.z = fmaxf(vv.z, 0.f); vv.w = fmaxf(vv.w, 0.f);
        float s = s_tab[l], cs = c_tab[l];
        *(float4*)&k_s[l][pad_col(d)]      = make_float4(kk.x*s,  kk.y*s,  kk.z*s,  kk.w*s);
        *(float4*)&k_s[l][pad_col(d + 64)] = make_float4(kk.x*cs, kk.y*cs, kk.z*cs, kk.w*cs);
        *(float4*)&v_s[l][d] = vv;
    }
    __syncthreads();

    // Column sums of k_ -> sumk (f32), computed once.
    if (tid < D2) {
        int pc = pad_col(tid);
        float ks = 0.f;
#pragma unroll
        for (int l = 0; l < T_CHUNK; ++l) ks += k_s[l][pc];
        sumk[(n * N_CHUNK + c) * D2 + tid] = ks;
    }

    const int g = tid & 7, mh = (tid >> 3) << 1;
    const int gbase = pad_col(16 * g);     // thread covers d2 = 16g .. 16g+15

    float st0[16], st1[16];
#pragma unroll
    for (int j = 0; j < 16; ++j) { st0[j] = 0.f; st1[j] = 0.f; }

    for (int l = 0; l < T_CHUNK; ++l) {
        float2 vm = *(const float2*)&v_s[l][mh];
        const float4* kv4 = (const float4*)&k_s[l][gbase];
#pragma unroll
        for (int jj = 0; jj < 4; ++jj) {
            float4 kk = kv4[jj];
            st0[4*jj+0] = fmaf(kk.x, vm.x, st0[4*jj+0]);
            st1[4*jj+0] = fmaf(kk.x, vm.y, st1[4*jj+0]);
            st0[4*jj+1] = fmaf(kk.y, vm.x, st0[4*jj+1]);
            st1[4*jj+1] = fmaf(kk.y, vm.y, st1[4*jj+1]);
            st0[4*jj+2] = fmaf(kk.z, vm.x, st0[4*jj+2]);
            st1[4*jj+2] = fmaf(kk.z, vm.y, st1[4*jj+2]);
            st0[4*jj+3] = fmaf(kk.w, vm.x, st0[4*jj+3]);
            st1[4*jj+3] = fmaf(kk.w, vm.y, st1[4*jj+3]);
        }
    }

    // Packed f16 store in [m][d2] layout: flat f16 index = m*128 + d2.
    // Thread holds (d2 = 16g..16g+15) x (m = mh, mh+1) -> uint4 idx m*16+2g.
    uint4* dst = (uint4*)(sumkv + (size_t)(n * N_CHUNK + c) * PK_UINTS);
    {
        int i0 = mh * 16 + (g << 1);
        int i1 = i0 + 16;                  // (mh+1)*16 + 2g
        dst[i0]     = make_uint4(packh2(st0[0],st0[1]),   packh2(st0[2],st0[3]),
                                 packh2(st0[4],st0[5]),   packh2(st0[6],st0[7]));
        dst[i0 + 1] = make_uint4(packh2(st0[8],st0[9]),   packh2(st0[10],st0[11]),
                                 packh2(st0[12],st0[13]), packh2(st0[14],st0[15]));
        dst[i1]     = make_uint4(packh2(st1[0],st1[1]),   packh2(st1[2],st1[3]),
                                 packh2(st1[4],st1[5]),   packh2(st1[6],st1[7]));
        dst[i1 + 1] = make_uint4(packh2(st1[8],st1[9]),   packh2(st1[10],st1[11]),
                                 packh2(st1[12],st1[13]), packh2(st1[14],st1[15]));
    }
}

// ---------------------------------------------------------------------------
// K2: exclusive prefix over chunks. Packed f16 storage, f32 accumulation.
// Layout-agnostic (elementwise over the flat buffer). Verbatim R9.
// ---------------------------------------------------------------------------
__global__ __launch_bounds__(256) void k2_prefix(
    unsigned int* __restrict__ sumkv, float* __restrict__ sumk)
{
    const int x = blockIdx.x, n = blockIdx.y;
    const int tid = threadIdx.x;

    if (x < 8) {
        uint2* base = (uint2*)(sumkv + (size_t)n * N_CHUNK * PK_UINTS) + x * 256 + tid;
        uint2 t[N_CHUNK];
#pragma unroll
        for (int c = 0; c < N_CHUNK; ++c) t[c] = base[c * (PK_UINTS / 2)];
        float r0 = 0.f, r1 = 0.f, r2 = 0.f, r3 = 0.f;
#pragma unroll
        for (int c = 0; c < N_CHUNK; ++c) {
            uint2 cur = t[c];
            base[c * (PK_UINTS / 2)] = make_uint2(packh2(r0, r1), packh2(r2, r3));
            float2 lo = unpackh2(cur.x), hi = unpackh2(cur.y);
            r0 += lo.x; r1 += lo.y; r2 += hi.x; r3 += hi.y;
        }
    } else if (tid < D2) {
        float* bk = sumk + n * N_CHUNK * D2 + tid;
        float t[N_CHUNK];
#pragma unroll
        for (int c = 0; c < N_CHUNK; ++c) t[c] = bk[c * D2];
        float r = 0.f;
#pragma unroll
        for (int c = 0; c < N_CHUNK; ++c) { bk[c * D2] = r; r += t[c]; }
    }
}

// ---------------------------------------------------------------------------
// K3: MFMA chunked linear attention.
//   S = Q_ K_^T (causal-masked)   [32x32, K=128]
//   O = Q_ S0 + P V               [32x64]
//   den[l] = q_.kc0 + rowsum(masked S)   (free from S frags)
// Fragment convention (v_mfma_f32_16x16x16_f16):
//   A lane: A[lane&15][4*(lane>>4)+j]; B lane: B^T[lane&15][4*(lane>>4)+j];
//   D lane reg r: row=(lane>>4)*4+r, col=lane&15.
// All operands staged row-major (M x K) / B-transposed (N x K) in LDS.
// ---------------------------------------------------------------------------
__global__ __launch_bounds__(256, 2) void k3_output(
    const float* __restrict__ q, const float* __restrict__ k,
    const float* __restrict__ v, const unsigned int* __restrict__ sumkv,
    const float* __restrict__ sumk, float* __restrict__ out)
{
    __shared__ __attribute__((aligned(16))) f16_t q16[T_CHUNK][PQ];
    __shared__ __attribute__((aligned(16))) f16_t k16[T_CHUNK][PQ];
    __shared__ __attribute__((aligned(16))) f16_t vt[D_HEAD][PV];   // V^T [m][l]
    __shared__ __attribute__((aligned(16))) f16_t s0t[D_HEAD][PS];  // S0^T [m][d2]
    __shared__ __attribute__((aligned(16))) f16_t pmat[T_CHUNK][PV];// P [l][l']
    __shared__ float kc0[D2];
    __shared__ float den0_s[T_CHUNK], dpA[T_CHUNK], dpB[T_CHUNK], rden[T_CHUNK];
    __shared__ float s_tab[T_CHUNK], c_tab[T_CHUNK];

    const int c = blockIdx.x, n = blockIdx.y;
    const int tid = threadIdx.x;
    const int base = (n * L_SEQ + c * T_CHUNK) * D_HEAD;

    if (tid < T_CHUNK) {
        float th = SINCOS_SCALE * (float)(c * T_CHUNK + tid + 1);
        s_tab[tid] = __sinf(th);
        c_tab[tid] = __cosf(th);
    }
    __syncthreads();

    // ---- Stage q_/k_ (row-major f16), V^T, S0^T, kc0 ----
    const float4* q4g = (const float4*)(q + base);
    const float4* k4g = (const float4*)(k + base);
    const float4* v4g = (const float4*)(v + base);
#pragma unroll
    for (int j = 0; j < 2; ++j) {
        int i4 = j * 256 + tid;
        int l = i4 >> 4, d = (i4 & 15) << 2;
        float4 kk = k4g[i4], qq = q4g[i4], vv = v4g[i4];
        kk.x = fmaxf(kk.x, 0.f); kk.y = fmaxf(kk.y, 0.f);
        kk.z = fmaxf(kk.z, 0.f); kk.w = fmaxf(kk.w, 0.f);
        qq.x = fmaxf(qq.x, 0.f); qq.y = fmaxf(qq.y, 0.f);
        qq.z = fmaxf(qq.z, 0.f); qq.w = fmaxf(qq.w, 0.f);
        vv.x = fmaxf(vv.x, 0.f); vv.y = fmaxf(vv.y, 0.f);
        vv.z = fmaxf(vv.z, 0.f); vv.w = fmaxf(vv.w, 0.f);
        float s = s_tab[l], cs = c_tab[l];
        q16[l][d+0]    = (f16_t)(qq.x*s);  q16[l][d+1]    = (f16_t)(qq.y*s);
        q16[l][d+2]    = (f16_t)(qq.z*s);  q16[l][d+3]    = (f16_t)(qq.w*s);
        q16[l][d+64]   = (f16_t)(qq.x*cs); q16[l][d+65]   = (f16_t)(qq.y*cs);
        q16[l][d+66]   = (f16_t)(qq.z*cs); q16[l][d+67]   = (f16_t)(qq.w*cs);
        k16[l][d+0]    = (f16_t)(kk.x*s);  k16[l][d+1]    = (f16_t)(kk.y*s);
        k16[l][d+2]    = (f16_t)(kk.z*s);  k16[l][d+3]    = (f16_t)(kk.w*s);
        k16[l][d+64]   = (f16_t)(kk.x*cs); k16[l][d+65]   = (f16_t)(kk.y*cs);
        k16[l][d+66]   = (f16_t)(kk.z*cs); k16[l][d+67]   = (f16_t)(kk.w*cs);
        vt[d+0][l] = (f16_t)vv.x; vt[d+1][l] = (f16_t)vv.y;
        vt[d+2][l] = (f16_t)vv.z; vt[d+3][l] = (f16_t)vv.w;
    }
    {
        const uint4* pkv = (const uint4*)(sumkv + (size_t)(n * N_CHUNK + c) * PK_UINTS);
#pragma unroll
        for (int jj = 0; jj < 4; ++jj) {
            int u = jj * 256 + tid;
            int pos = u << 3;                       // flat f16 index
            *(uint4*)&s0t[pos >> 7][pos & 127] = pkv[u];
        }
    }
    if (tid < D2) kc0[tid] = sumk[(n * N_CHUNK + c) * D2 + tid];
    __syncthreads();

    // ---- den0[l] = q_[l] . kc0 (all threads; 8 lanes per row) ----
    {
        int l = tid >> 3, seg = (tid & 7) << 4;
        float a = 0.f;
#pragma unroll
        for (int i = 0; i < 16; ++i) a += (float)q16[l][seg + i] * kc0[seg + i];
        a = red8_dpp(a);
        if ((tid & 7) == 0) den0_s[l] = a;
    }

    const int wave = tid >> 6, lane = tid & 63;
    const int fr = lane & 15;            // fragment row/col (lane%16)
    const int fk = (lane >> 4) << 2;     // fragment k offset
    const int rowq = (lane >> 4) << 2;   // C/D row base

    // ---- S phase: tiles (0,0),(1,0),(1,1); (0,1) is fully masked ----
    if (wave < 3) {
        const int mt = (wave == 0) ? 0 : 1;
        const int nt = (wave == 2) ? 1 : 0;
        f32x4 sa = {0.f, 0.f, 0.f, 0.f};
#pragma unroll
        for (int ks = 0; ks < 8; ++ks) {
            f16x4 a = *(const f16x4*)&q16[mt * 16 + fr][ks * 16 + fk];
            f16x4 b = *(const f16x4*)&k16[nt * 16 + fr][ks * 16 + fk];
            sa = mfma16(a, b, sa);
        }
#pragma unroll
        for (int r = 0; r < 4; ++r) {
            int row = rowq + r;
            float mv = (mt > nt || fr <= row) ? sa[r] : 0.f;   // causal: l' <= l
            pmat[mt * 16 + row][nt * 16 + fr] = (f16_t)mv;
            float rs = red16_dpp(mv);
            if (fr == 0) {
                if (wave == 2) dpB[16 + row] = rs;
                else dpA[mt * 16 + row] = rs;
            }
        }
    } else {
        // zero P tile (0,1): rows 0..15, cols 16..31
        int row = lane >> 2, colb = 16 + ((lane & 3) << 2);
        *(uint2*)&pmat[row][colb] = make_uint2(0u, 0u);
    }
    __syncthreads();

    if (tid < T_CHUNK) {
        float den = den0_s[tid] + dpA[tid] + ((tid >= 16) ? dpB[tid] : 0.f);
        rden[tid] = 1.f / fmaxf(den, 1e-6f);
    }

    // ---- O phase: O = Q_ @ S0 + P @ V ; 2x4 tiles, 2 per wave ----
    const int mt = wave >> 1;
    const int nt0 = (wave & 1) << 1, nt1 = nt0 + 1;
    f32x4 o0 = {0.f, 0.f, 0.f, 0.f}, o1 = {0.f, 0.f, 0.f, 0.f};
#pragma unroll
    for (int ks = 0; ks < 8; ++ks) {
        f16x4 a  = *(const f16x4*)&q16[mt * 16 + fr][ks * 16 + fk];
        f16x4 b0 = *(const f16x4*)&s0t[nt0 * 16 + fr][ks * 16 + fk];
        f16x4 b1 = *(const f16x4*)&s0t[nt1 * 16 + fr][ks * 16 + fk];
        o0 = mfma16(a, b0, o0);
        o1 = mfma16(a, b1, o1);
    }
#pragma unroll
    for (int ks = 0; ks < 2; ++ks) {
        f16x4 a  = *(const f16x4*)&pmat[mt * 16 + fr][ks * 16 + fk];
        f16x4 b0 = *(const f16x4*)&vt[nt0 * 16 + fr][ks * 16 + fk];
        f16x4 b1 = *(const f16x4*)&vt[nt1 * 16 + fr][ks * 16 + fk];
        o0 = mfma16(a, b0, o0);
        o1 = mfma16(a, b1, o1);
    }
    __syncthreads();   // rden ready

    float* og = out + base;
#pragma unroll
    for (int r = 0; r < 4; ++r) {
        int row = mt * 16 + rowq + r;
        float rd = rden[row];
        og[row * D_HEAD + nt0 * 16 + fr] = o0[r] * rd;
        og[row * D_HEAD + nt1 * 16 + fr] = o1[r] * rd;
    }
}

// ---------------------------------------------------------------------------
extern "C" void kernel_launch(void* const* d_in, const int* in_sizes, int n_in,
                              void* d_out, int out_size, void* d_ws, size_t ws_size,
                              hipStream_t stream) {
    (void)in_sizes; (void)n_in; (void)out_size; (void)ws_size;
    const float* q = (const float*)d_in[0];
    const float* k = (const float*)d_in[1];
    const float* v = (const float*)d_in[2];
    float* out = (float*)d_out;

    unsigned int* sumkv = (unsigned int*)d_ws;                         // packed f16 [N][C][m][d2]
    float* sumk = (float*)(sumkv + (size_t)N_HEADS * N_CHUNK * PK_UINTS); // f32 [N][C][128]

    dim3 grid(N_CHUNK, N_HEADS);
    k1_chunk_sums<<<grid, 256, 0, stream>>>(k, v, sumkv, sumk);
    dim3 grid2(9, N_HEADS);
    k2_prefix<<<grid2, 256, 0, stream>>>(sumkv, sumk);
    k3_output<<<grid, 256, 0, stream>>>(q, k, v, sumkv, sumk, out);
}

// Round 12
// 76.037 us; speedup vs baseline: 1.3596x; 1.0394x over previous
//
#include <hip/hip_runtime.h>
#include <hip/hip_fp16.h>

// Problem constants (B=2, H=8, L=1024, D=64)
#define N_HEADS 16          // B*H
#define L_SEQ   1024
#define D_HEAD  64
#define D2      128         // 2*D (sin/cos concat)
#define T_CHUNK 32
#define N_CHUNK (L_SEQ / T_CHUNK)   // 32
#define KV_ELEMS (D2 * D_HEAD)      // 8192 f16 values per chunk
#define PK_UINTS (KV_ELEMS / 2)     // 4096 packed half2 per chunk

// f16 LDS pitches (elements):
#define PQ 132   // q16/k16 [32][PQ]   (264B rows, conflict-free frag reads)
#define PS 136   // s0t/ob  [64][PS]   (272B rows = 17x16B: uint4-aligned)
#define PV 36    // vt/k16t/pmat       (72B rows, conflict-free frag reads)

#define SINCOS_SCALE 1.53398078788564122971e-3f   // (pi/2)/1024

typedef _Float16 f16_t;
typedef __attribute__((ext_vector_type(4))) _Float16 f16x4;
typedef __attribute__((ext_vector_type(4))) float f32x4;

__device__ __forceinline__ f32x4 mfma16(f16x4 a, f16x4 b, f32x4 c) {
    return __builtin_amdgcn_mfma_f32_16x16x16f16(a, b, c, 0, 0, 0);
}

// f16 pack helpers (storage only; accumulation stays f32)
__device__ __forceinline__ unsigned int packh2(float a, float b) {
    __half2 h = __floats2half2_rn(a, b);
    return __builtin_bit_cast(unsigned int, h);
}
__device__ __forceinline__ float2 unpackh2(unsigned int u) {
    __half2 h = __builtin_bit_cast(__half2, u);
    return __half22float2(h);
}

// All-VALU (DPP) reductions.
__device__ __forceinline__ float red8_dpp(float x) {
    x += __int_as_float(__builtin_amdgcn_mov_dpp(__float_as_int(x), 0xB1, 0xF, 0xF, true));
    x += __int_as_float(__builtin_amdgcn_mov_dpp(__float_as_int(x), 0x4E, 0xF, 0xF, true));
    x += __int_as_float(__builtin_amdgcn_mov_dpp(__float_as_int(x), 0x141, 0xF, 0xF, true));
    return x;
}
__device__ __forceinline__ float red16_dpp(float x) {
    x += __int_as_float(__builtin_amdgcn_mov_dpp(__float_as_int(x), 0xB1, 0xF, 0xF, true));
    x += __int_as_float(__builtin_amdgcn_mov_dpp(__float_as_int(x), 0x4E, 0xF, 0xF, true));
    x += __int_as_float(__builtin_amdgcn_mov_dpp(__float_as_int(x), 0x141, 0xF, 0xF, true));
    x += __int_as_float(__builtin_amdgcn_mov_dpp(__float_as_int(x), 0x140, 0xF, 0xF, true));
    return x;
}

// ---------------------------------------------------------------------------
// K1: sumkv^T[m][d2] = sum_l V^T[m][l] K_[l][d2]  -- a 64x128, K=32 GEMM on
// matrix cores. A = V^T (vt rows), B^T = K_^T (k16t rows). 4 waves (mt=wave)
// x 8 N-tiles x 2 K-steps = 64 MFMAs/block. Output bounced via LDS for
// coalesced uint4 stores in the [m][d2] flat layout K3 consumes.
// ---------------------------------------------------------------------------
__global__ __launch_bounds__(256, 2) void k1_chunk_sums(
    const float* __restrict__ k, const float* __restrict__ v,
    unsigned int* __restrict__ sumkv, float* __restrict__ sumk)
{
    __shared__ __attribute__((aligned(16))) f16_t k16t[D2][PV];     // K_^T [d2][l]
    __shared__ __attribute__((aligned(16))) f16_t vt1[D_HEAD][PV];  // V^T  [m][l]
    __shared__ __attribute__((aligned(16))) f16_t ob[D_HEAD][PS];   // out  [m][d2]
    __shared__ float s_tab[T_CHUNK], c_tab[T_CHUNK];

    const int c = blockIdx.x, n = blockIdx.y;
    const int tid = threadIdx.x;
    const int base = (n * L_SEQ + c * T_CHUNK) * D_HEAD;

    if (tid < T_CHUNK) {
        float th = SINCOS_SCALE * (float)(c * T_CHUNK + tid + 1);
        s_tab[tid] = __sinf(th);
        c_tab[tid] = __cosf(th);
    }
    __syncthreads();

    // Stage: relu + reweight, transposed f16 into LDS.
    const float4* k4g = (const float4*)(k + base);
    const float4* v4g = (const float4*)(v + base);
#pragma unroll
    for (int j = 0; j < 2; ++j) {
        int i4 = j * 256 + tid;            // 0..511
        int l = i4 >> 4, d = (i4 & 15) << 2;
        float4 kk = k4g[i4], vv = v4g[i4];
        kk.x = fmaxf(kk.x, 0.f); kk.y = fmaxf(kk.y, 0.f);
        kk.z = fmaxf(kk.z, 0.f); kk.w = fmaxf(kk.w, 0.f);
        vv.x = fmaxf(vv.x, 0.f); vv.y = fmaxf(vv.y, 0.f);
        vv.z = fmaxf(vv.z, 0.f); vv.w = fmaxf(vv.w, 0.f);
        float s = s_tab[l], cs = c_tab[l];
        k16t[d+0][l]    = (f16_t)(kk.x*s);  k16t[d+1][l]    = (f16_t)(kk.y*s);
        k16t[d+2][l]    = (f16_t)(kk.z*s);  k16t[d+3][l]    = (f16_t)(kk.w*s);
        k16t[d+64][l]   = (f16_t)(kk.x*cs); k16t[d+65][l]   = (f16_t)(kk.y*cs);
        k16t[d+66][l]   = (f16_t)(kk.z*cs); k16t[d+67][l]   = (f16_t)(kk.w*cs);
        vt1[d+0][l] = (f16_t)vv.x; vt1[d+1][l] = (f16_t)vv.y;
        vt1[d+2][l] = (f16_t)vv.z; vt1[d+3][l] = (f16_t)vv.w;
    }
    __syncthreads();

    // sumk[d2] = sum_l k16t[d2][l] (f32 accum over f16 values).
    if (tid < D2) {
        const f16x4* row = (const f16x4*)&k16t[tid][0];
        float acc = 0.f;
#pragma unroll
        for (int i = 0; i < 8; ++i) {
            f16x4 x = row[i];
            acc += ((float)x[0] + (float)x[1]) + ((float)x[2] + (float)x[3]);
        }
        sumk[(n * N_CHUNK + c) * D2 + tid] = acc;
    }

    const int wave = tid >> 6, lane = tid & 63;
    const int fr = lane & 15;            // A/B fragment row (m or d2 within tile)
    const int fk = (lane >> 4) << 2;     // fragment K offset; also D row base

    // A fragments (V^T rows, fixed mt = wave), K=32 in two steps.
    f16x4 a0 = *(const f16x4*)&vt1[wave * 16 + fr][fk];
    f16x4 a1 = *(const f16x4*)&vt1[wave * 16 + fr][16 + fk];

    f32x4 acc[8];
#pragma unroll
    for (int nt = 0; nt < 8; ++nt) acc[nt] = (f32x4){0.f, 0.f, 0.f, 0.f};
#pragma unroll
    for (int nt = 0; nt < 8; ++nt) {
        f16x4 b0 = *(const f16x4*)&k16t[nt * 16 + fr][fk];
        f16x4 b1 = *(const f16x4*)&k16t[nt * 16 + fr][16 + fk];
        acc[nt] = mfma16(a0, b0, acc[nt]);
        acc[nt] = mfma16(a1, b1, acc[nt]);
    }

    // D (row=m, col=d2) -> LDS bounce (f16), then coalesced uint4 store.
#pragma unroll
    for (int nt = 0; nt < 8; ++nt)
#pragma unroll
        for (int r = 0; r < 4; ++r)
            ob[wave * 16 + fk + r][nt * 16 + fr] = (f16_t)acc[nt][r];
    __syncthreads();

    uint4* dst = (uint4*)(sumkv + (size_t)(n * N_CHUNK + c) * PK_UINTS);
#pragma unroll
    for (int t = 0; t < 4; ++t) {
        int u = t * 256 + tid;             // 0..1023; flat f16 = m*128 + 8*(u&15)
        dst[u] = *(const uint4*)&ob[u >> 4][(u & 15) * 8];
    }
}

// ---------------------------------------------------------------------------
// K2: exclusive prefix over chunks. Packed f16 storage, f32 accumulation.
// Layout-agnostic (elementwise over the flat buffer). Verbatim R9/R11.
// ---------------------------------------------------------------------------
__global__ __launch_bounds__(256) void k2_prefix(
    unsigned int* __restrict__ sumkv, float* __restrict__ sumk)
{
    const int x = blockIdx.x, n = blockIdx.y;
    const int tid = threadIdx.x;

    if (x < 8) {
        uint2* base = (uint2*)(sumkv + (size_t)n * N_CHUNK * PK_UINTS) + x * 256 + tid;
        uint2 t[N_CHUNK];
#pragma unroll
        for (int c = 0; c < N_CHUNK; ++c) t[c] = base[c * (PK_UINTS / 2)];
        float r0 = 0.f, r1 = 0.f, r2 = 0.f, r3 = 0.f;
#pragma unroll
        for (int c = 0; c < N_CHUNK; ++c) {
            uint2 cur = t[c];
            base[c * (PK_UINTS / 2)] = make_uint2(packh2(r0, r1), packh2(r2, r3));
            float2 lo = unpackh2(cur.x), hi = unpackh2(cur.y);
            r0 += lo.x; r1 += lo.y; r2 += hi.x; r3 += hi.y;
        }
    } else if (tid < D2) {
        float* bk = sumk + n * N_CHUNK * D2 + tid;
        float t[N_CHUNK];
#pragma unroll
        for (int c = 0; c < N_CHUNK; ++c) t[c] = bk[c * D2];
        float r = 0.f;
#pragma unroll
        for (int c = 0; c < N_CHUNK; ++c) { bk[c * D2] = r; r += t[c]; }
    }
}

// ---------------------------------------------------------------------------
// K3: MFMA chunked linear attention. Verbatim R11 (proven at 79.0 us).
// ---------------------------------------------------------------------------
__global__ __launch_bounds__(256, 2) void k3_output(
    const float* __restrict__ q, const float* __restrict__ k,
    const float* __restrict__ v, const unsigned int* __restrict__ sumkv,
    const float* __restrict__ sumk, float* __restrict__ out)
{
    __shared__ __attribute__((aligned(16))) f16_t q16[T_CHUNK][PQ];
    __shared__ __attribute__((aligned(16))) f16_t k16[T_CHUNK][PQ];
    __shared__ __attribute__((aligned(16))) f16_t vt[D_HEAD][PV];   // V^T [m][l]
    __shared__ __attribute__((aligned(16))) f16_t s0t[D_HEAD][PS];  // S0^T [m][d2]
    __shared__ __attribute__((aligned(16))) f16_t pmat[T_CHUNK][PV];// P [l][l']
    __shared__ float kc0[D2];
    __shared__ float den0_s[T_CHUNK], dpA[T_CHUNK], dpB[T_CHUNK], rden[T_CHUNK];
    __shared__ float s_tab[T_CHUNK], c_tab[T_CHUNK];

    const int c = blockIdx.x, n = blockIdx.y;
    const int tid = threadIdx.x;
    const int base = (n * L_SEQ + c * T_CHUNK) * D_HEAD;

    if (tid < T_CHUNK) {
        float th = SINCOS_SCALE * (float)(c * T_CHUNK + tid + 1);
        s_tab[tid] = __sinf(th);
        c_tab[tid] = __cosf(th);
    }
    __syncthreads();

    // ---- Stage q_/k_ (row-major f16), V^T, S0^T, kc0 ----
    const float4* q4g = (const float4*)(q + base);
    const float4* k4g = (const float4*)(k + base);
    const float4* v4g = (const float4*)(v + base);
#pragma unroll
    for (int j = 0; j < 2; ++j) {
        int i4 = j * 256 + tid;
        int l = i4 >> 4, d = (i4 & 15) << 2;
        float4 kk = k4g[i4], qq = q4g[i4], vv = v4g[i4];
        kk.x = fmaxf(kk.x, 0.f); kk.y = fmaxf(kk.y, 0.f);
        kk.z = fmaxf(kk.z, 0.f); kk.w = fmaxf(kk.w, 0.f);
        qq.x = fmaxf(qq.x, 0.f); qq.y = fmaxf(qq.y, 0.f);
        qq.z = fmaxf(qq.z, 0.f); qq.w = fmaxf(qq.w, 0.f);
        vv.x = fmaxf(vv.x, 0.f); vv.y = fmaxf(vv.y, 0.f);
        vv.z = fmaxf(vv.z, 0.f); vv.w = fmaxf(vv.w, 0.f);
        float s = s_tab[l], cs = c_tab[l];
        q16[l][d+0]    = (f16_t)(qq.x*s);  q16[l][d+1]    = (f16_t)(qq.y*s);
        q16[l][d+2]    = (f16_t)(qq.z*s);  q16[l][d+3]    = (f16_t)(qq.w*s);
        q16[l][d+64]   = (f16_t)(qq.x*cs); q16[l][d+65]   = (f16_t)(qq.y*cs);
        q16[l][d+66]   = (f16_t)(qq.z*cs); q16[l][d+67]   = (f16_t)(qq.w*cs);
        k16[l][d+0]    = (f16_t)(kk.x*s);  k16[l][d+1]    = (f16_t)(kk.y*s);
        k16[l][d+2]    = (f16_t)(kk.z*s);  k16[l][d+3]    = (f16_t)(kk.w*s);
        k16[l][d+64]   = (f16_t)(kk.x*cs); k16[l][d+65]   = (f16_t)(kk.y*cs);
        k16[l][d+66]   = (f16_t)(kk.z*cs); k16[l][d+67]   = (f16_t)(kk.w*cs);
        vt[d+0][l] = (f16_t)vv.x; vt[d+1][l] = (f16_t)vv.y;
        vt[d+2][l] = (f16_t)vv.z; vt[d+3][l] = (f16_t)vv.w;
    }
    {
        const uint4* pkv = (const uint4*)(sumkv + (size_t)(n * N_CHUNK + c) * PK_UINTS);
#pragma unroll
        for (int jj = 0; jj < 4; ++jj) {
            int u = jj * 256 + tid;
            int pos = u << 3;                       // flat f16 index
            *(uint4*)&s0t[pos >> 7][pos & 127] = pkv[u];
        }
    }
    if (tid < D2) kc0[tid] = sumk[(n * N_CHUNK + c) * D2 + tid];
    __syncthreads();

    // ---- den0[l] = q_[l] . kc0 (all threads; 8 lanes per row) ----
    {
        int l = tid >> 3, seg = (tid & 7) << 4;
        float a = 0.f;
#pragma unroll
        for (int i = 0; i < 16; ++i) a += (float)q16[l][seg + i] * kc0[seg + i];
        a = red8_dpp(a);
        if ((tid & 7) == 0) den0_s[l] = a;
    }

    const int wave = tid >> 6, lane = tid & 63;
    const int fr = lane & 15;            // fragment row/col (lane%16)
    const int fk = (lane >> 4) << 2;     // fragment k offset
    const int rowq = (lane >> 4) << 2;   // C/D row base

    // ---- S phase: tiles (0,0),(1,0),(1,1); (0,1) is fully masked ----
    if (wave < 3) {
        const int mt = (wave == 0) ? 0 : 1;
        const int nt = (wave == 2) ? 1 : 0;
        f32x4 sa = {0.f, 0.f, 0.f, 0.f};
#pragma unroll
        for (int ks = 0; ks < 8; ++ks) {
            f16x4 a = *(const f16x4*)&q16[mt * 16 + fr][ks * 16 + fk];
            f16x4 b = *(const f16x4*)&k16[nt * 16 + fr][ks * 16 + fk];
            sa = mfma16(a, b, sa);
        }
#pragma unroll
        for (int r = 0; r < 4; ++r) {
            int row = rowq + r;
            float mv = (mt > nt || fr <= row) ? sa[r] : 0.f;   // causal: l' <= l
            pmat[mt * 16 + row][nt * 16 + fr] = (f16_t)mv;
            float rs = red16_dpp(mv);
            if (fr == 0) {
                if (wave == 2) dpB[16 + row] = rs;
                else dpA[mt * 16 + row] = rs;
            }
        }
    } else {
        // zero P tile (0,1): rows 0..15, cols 16..31
        int row = lane >> 2, colb = 16 + ((lane & 3) << 2);
        *(uint2*)&pmat[row][colb] = make_uint2(0u, 0u);
    }
    __syncthreads();

    if (tid < T_CHUNK) {
        float den = den0_s[tid] + dpA[tid] + ((tid >= 16) ? dpB[tid] : 0.f);
        rden[tid] = 1.f / fmaxf(den, 1e-6f);
    }

    // ---- O phase: O = Q_ @ S0 + P @ V ; 2x4 tiles, 2 per wave ----
    const int mt = wave >> 1;
    const int nt0 = (wave & 1) << 1, nt1 = nt0 + 1;
    f32x4 o0 = {0.f, 0.f, 0.f, 0.f}, o1 = {0.f, 0.f, 0.f, 0.f};
#pragma unroll
    for (int ks = 0; ks < 8; ++ks) {
        f16x4 a  = *(const f16x4*)&q16[mt * 16 + fr][ks * 16 + fk];
        f16x4 b0 = *(const f16x4*)&s0t[nt0 * 16 + fr][ks * 16 + fk];
        f16x4 b1 = *(const f16x4*)&s0t[nt1 * 16 + fr][ks * 16 + fk];
        o0 = mfma16(a, b0, o0);
        o1 = mfma16(a, b1, o1);
    }
#pragma unroll
    for (int ks = 0; ks < 2; ++ks) {
        f16x4 a  = *(const f16x4*)&pmat[mt * 16 + fr][ks * 16 + fk];
        f16x4 b0 = *(const f16x4*)&vt[nt0 * 16 + fr][ks * 16 + fk];
        f16x4 b1 = *(const f16x4*)&vt[nt1 * 16 + fr][ks * 16 + fk];
        o0 = mfma16(a, b0, o0);
        o1 = mfma16(a, b1, o1);
    }
    __syncthreads();   // rden ready

    float* og = out + base;
#pragma unroll
    for (int r = 0; r < 4; ++r) {
        int row = mt * 16 + rowq + r;
        float rd = rden[row];
        og[row * D_HEAD + nt0 * 16 + fr] = o0[r] * rd;
        og[row * D_HEAD + nt1 * 16 + fr] = o1[r] * rd;
    }
}

// ---------------------------------------------------------------------------
extern "C" void kernel_launch(void* const* d_in, const int* in_sizes, int n_in,
                              void* d_out, int out_size, void* d_ws, size_t ws_size,
                              hipStream_t stream) {
    (void)in_sizes; (void)n_in; (void)out_size; (void)ws_size;
    const float* q = (const float*)d_in[0];
    const float* k = (const float*)d_in[1];
    const float* v = (const float*)d_in[2];
    float* out = (float*)d_out;

    unsigned int* sumkv = (unsigned int*)d_ws;                         // packed f16 [N][C][m][d2]
    float* sumk = (float*)(sumkv + (size_t)N_HEADS * N_CHUNK * PK_UINTS); // f32 [N][C][128]

    dim3 grid(N_CHUNK, N_HEADS);
    k1_chunk_sums<<<grid, 256, 0, stream>>>(k, v, sumkv, sumk);
    dim3 grid2(9, N_HEADS);
    k2_prefix<<<grid2, 256, 0, stream>>>(sumkv, sumk);
    k3_output<<<grid, 256, 0, stream>>>(q, k, v, sumkv, sumk, out);
}